// Round 6
// baseline (411.674 us; speedup 1.0000x reference)
//
#include <hip/hip_runtime.h>
#include <math.h>

#define BATCH 16384
#define INPUT_DIM 512
#define HIDDEN 1024
#define NROT 32
#define NANG 496   // 32*31/2

typedef _Float16 half8 __attribute__((ext_vector_type(8)));
typedef float    f32x4 __attribute__((ext_vector_type(4)));

// ---------------------------------------------------------------------------
// Split-precision f16 MFMA GEMM (NT): C = epi(A[M,K] @ B[N,K]^T + bias)
// (unchanged — not the bottleneck)
// ---------------------------------------------------------------------------
template<int EPI>
__global__ __launch_bounds__(256) void gemm_nt_mfma(
    const float* __restrict__ A, const float* __restrict__ B,
    const float* __restrict__ bias, float* __restrict__ C,
    int M, int N, int K, int Nout)
{
    constexpr int BK = 32;                    // K per stage (f32 elems)
    __shared__ _Float16 sAh[2][128 * BK];
    __shared__ _Float16 sAl[2][128 * BK];
    __shared__ _Float16 sB [2][128 * BK];     // total 48 KB

    const int tid = threadIdx.x;
    const int m0 = blockIdx.y * 128;
    const int n0 = blockIdx.x * 128;

    const int rA  = tid >> 2;                       // 0..63
    const int k8  = tid & 3;
    const int swW = ((k8 ^ (rA & 3)) << 3);         // swizzled f16 offset in row

    float4 rg[4][2];

    auto load_tile = [&](int kt) {
        const size_t koff = (size_t)kt * BK + k8 * 8;
        const float4* p;
        p = (const float4*)(A + (size_t)(m0 + rA) * K + koff);
        rg[0][0] = p[0]; rg[0][1] = p[1];
        p = (const float4*)(A + (size_t)(m0 + rA + 64) * K + koff);
        rg[1][0] = p[0]; rg[1][1] = p[1];
        const float4 z = make_float4(0.f, 0.f, 0.f, 0.f);
        if (EPI == 0 || (n0 + rA) < N) {
            p = (const float4*)(B + (size_t)(n0 + rA) * K + koff);
            rg[2][0] = p[0]; rg[2][1] = p[1];
        } else { rg[2][0] = z; rg[2][1] = z; }
        if (EPI == 0 || (n0 + rA + 64) < N) {
            p = (const float4*)(B + (size_t)(n0 + rA + 64) * K + koff);
            rg[3][0] = p[0]; rg[3][1] = p[1];
        } else { rg[3][0] = z; rg[3][1] = z; }
    };

    auto cvt_write = [&](int buf) {
        #pragma unroll
        for (int h = 0; h < 2; ++h) {
            const int base = (rA + h * 64) * BK + swW;
            half8 hi, lo;
            const float* f = (const float*)&rg[h][0];
            #pragma unroll
            for (int j = 0; j < 8; ++j) {
                _Float16 hv = (_Float16)f[j];
                hi[j] = hv;
                lo[j] = (_Float16)(f[j] - (float)hv);
            }
            *(half8*)&sAh[buf][base] = hi;
            *(half8*)&sAl[buf][base] = lo;
        }
        #pragma unroll
        for (int h = 0; h < 2; ++h) {
            const int base = (rA + h * 64) * BK + swW;
            half8 bv;
            const float* f = (const float*)&rg[2 + h][0];
            #pragma unroll
            for (int j = 0; j < 8; ++j) bv[j] = (_Float16)f[j];
            *(half8*)&sB[buf][base] = bv;
        }
    };

    const int lane = tid & 63;
    const int wid  = tid >> 6;
    const int wr = wid >> 1, wc = wid & 1;
    const int fr = lane & 15, fq = lane >> 4;
    const int swR   = ((fq ^ (fr & 3)) << 3);
    const int aBase = (wr * 64 + fr) * BK + swR;
    const int bBase = (wc * 64 + fr) * BK + swR;

    f32x4 acc[4][4];
    #pragma unroll
    for (int i = 0; i < 4; ++i)
        #pragma unroll
        for (int j = 0; j < 4; ++j) acc[i][j] = (f32x4)(0.f);

    const int NT = K / BK;
    load_tile(0);
    cvt_write(0);
    int cur = 0;

    for (int kt = 0; kt < NT; ++kt) {
        const bool more = (kt + 1 < NT);
        if (more) load_tile(kt + 1);
        __syncthreads();

        half8 ah[4], al[4], bb[4];
        #pragma unroll
        for (int f = 0; f < 4; ++f) {
            ah[f] = *(const half8*)&sAh[cur][aBase + f * 16 * BK];
            al[f] = *(const half8*)&sAl[cur][aBase + f * 16 * BK];
            bb[f] = *(const half8*)&sB [cur][bBase + f * 16 * BK];
        }
        #pragma unroll
        for (int fm = 0; fm < 4; ++fm)
            #pragma unroll
            for (int fn = 0; fn < 4; ++fn) {
                acc[fm][fn] = __builtin_amdgcn_mfma_f32_16x16x32_f16(
                    al[fm], bb[fn], acc[fm][fn], 0, 0, 0);
                acc[fm][fn] = __builtin_amdgcn_mfma_f32_16x16x32_f16(
                    ah[fm], bb[fn], acc[fm][fn], 0, 0, 0);
            }

        if (more) cvt_write(cur ^ 1);
        cur ^= 1;
    }

    if (EPI == 0) {
        #pragma unroll
        for (int fn = 0; fn < 4; ++fn) {
            const int col = n0 + wc * 64 + fn * 16 + fr;
            const float bv = bias[col];
            #pragma unroll
            for (int fm = 0; fm < 4; ++fm) {
                const int row0 = m0 + wr * 64 + fm * 16 + fq * 4;
                #pragma unroll
                for (int r = 0; r < 4; ++r)
                    C[(size_t)(row0 + r) * Nout + col] =
                        fmaxf(acc[fm][fn][r] + bv, 0.f);
            }
        }
    } else {
        #pragma unroll
        for (int fn = 0; fn < 4; ++fn) {
            const int col = n0 + wc * 64 + fn * 16 + fr;
            if (col < Nout) {
                const float bv = bias[col];
                #pragma unroll
                for (int fm = 0; fm < 4; ++fm) {
                    const int row0 = m0 + wr * 64 + fm * 16 + fq * 4;
                    #pragma unroll
                    for (int r = 0; r < 4; ++r) {
                        const float ang = acc[fm][fn][r] + bv;
                        float s, c;
                        __sincosf(ang, &s, &c);
                        *(float2*)(C + ((size_t)(row0 + r) * Nout + col) * 2) =
                            make_float2(c, s);
                    }
                }
            }
        }
    }
}

// ---------------------------------------------------------------------------
// Givens rotation chain — ds_swizzle broadcast, template-unrolled so every
// swizzle pattern is an integer constant expression (round-5 compile fix).
//   - Half-wave (32 lanes) = one batch element's 32 rows.
//   - 248 cs float4s distributed across 32 lanes (8 coalesced loads/thread,
//     issued once -> no per-rotation load-latency chain).
//   - Per float4 (2 rotations): 4x ds_swizzle_b32 BitMode (and=0,or=owner):
//     broadcasts lane `owner` within each 32-lane group. Register-only,
//     no LDS storage, no barrier.
//   - Output via XOR-swizzled LDS transpose -> contiguous global stores.
// ---------------------------------------------------------------------------
struct IJTbl { unsigned char i[NANG]; unsigned char j[NANG]; };
constexpr IJTbl make_ij_tbl() {
    IJTbl t{};
    int k = 0;
    for (int i = 0; i < NROT - 1; ++i)
        for (int j = i + 1; j < NROT; ++j) { t.i[k] = (unsigned char)i; t.j[k] = (unsigned char)j; ++k; }
    return t;
}
constexpr IJTbl IJT = make_ij_tbl();

__device__ __forceinline__ float bcast32(float x, int pat_dummy, float& dst) {
    return dst = x; // unused helper placeholder (kept out of final path)
}

template<int F>
__device__ __forceinline__ void rot_step(const float4 (&d)[8], float (&v)[NROT]) {
    constexpr int reg   = F >> 5;
    constexpr int owner = F & 31;
    constexpr int pat   = owner << 5;   // BitMode: and=0, or=owner, xor=0
    const float c0 = __int_as_float(__builtin_amdgcn_ds_swizzle(__float_as_int(d[reg].x), pat));
    const float s0 = __int_as_float(__builtin_amdgcn_ds_swizzle(__float_as_int(d[reg].y), pat));
    const float c1 = __int_as_float(__builtin_amdgcn_ds_swizzle(__float_as_int(d[reg].z), pat));
    const float s1 = __int_as_float(__builtin_amdgcn_ds_swizzle(__float_as_int(d[reg].w), pat));
    {
        constexpr int k = 2 * F;
        constexpr int i = IJT.i[k], j = IJT.j[k];
        const float vi = v[i], vj = v[j];
        v[i] = fmaf(c0, vi,  s0 * vj);
        v[j] = fmaf(c0, vj, -s0 * vi);
    }
    {
        constexpr int k = 2 * F + 1;
        constexpr int i = IJT.i[k], j = IJT.j[k];
        const float vi = v[i], vj = v[j];
        v[i] = fmaf(c1, vi,  s1 * vj);
        v[j] = fmaf(c1, vj, -s1 * vi);
    }
}

template<int F, int END>
struct Chain {
    __device__ __forceinline__ static void run(const float4 (&d)[8], float (&v)[NROT]) {
        rot_step<F>(d, v);
        Chain<F + 1, END>::run(d, v);
    }
};
template<int END>
struct Chain<END, END> {
    __device__ __forceinline__ static void run(const float4 (&)[8], float (&)[NROT]) {}
};

__global__ __launch_bounds__(256, 4) void rotate_kernel(
    const float4* __restrict__ cs4, float* __restrict__ out)
{
    __shared__ float lds[8192];   // 32 KB: output transpose staging

    const int tid  = threadIdx.x;
    const int lane = tid & 63;
    const int hl   = lane & 31;            // lane within half-wave
    const int g = blockIdx.x * 256 + tid;
    const int b = g >> 5;                  // batch element
    const int r = g & 31;                  // row of R

    const float4* __restrict__ p = cs4 + (size_t)b * (NANG / 2);

    // distribute: lane hl owns f4 indices { q*32 + hl }, q=0..7 (clamped tail)
    float4 d[8];
    #pragma unroll
    for (int q = 0; q < 8; ++q) {
        int idx = q * 32 + hl;
        if (idx > NANG / 2 - 1) idx = NANG / 2 - 1;   // lanes 24..31 @ q=7: never broadcast
        d[q] = p[idx];
    }

    float v[NROT];
    #pragma unroll
    for (int c = 0; c < NROT; ++c) v[c] = (c == r) ? 1.f : 0.f;

    Chain<0, NANG / 2>::run(d, v);

    // ---- coalesced store via swizzled LDS transpose ----
    #pragma unroll
    for (int q = 0; q < 8; ++q) {
        *(float4*)&lds[tid * 32 + ((q ^ (tid & 7)) << 2)] =
            make_float4(v[q*4], v[q*4+1], v[q*4+2], v[q*4+3]);
    }
    __syncthreads();

    float* obase = out + (size_t)blockIdx.x * 8192;
    #pragma unroll
    for (int s = 0; s < 8; ++s) {
        const int f4  = s * 256 + tid;
        const int row = f4 >> 3;
        const int qq  = f4 & 7;
        const float4 val = *(const float4*)&lds[row * 32 + ((qq ^ (row & 7)) << 2)];
        *(float4*)(obase + (size_t)f4 * 4) = val;
    }
}

// ---------------------------------------------------------------------------
extern "C" void kernel_launch(void* const* d_in, const int* in_sizes, int n_in,
                              void* d_out, int out_size, void* d_ws, size_t ws_size,
                              hipStream_t stream)
{
    const float* x  = (const float*)d_in[0];   // [16384, 512]
    const float* W1 = (const float*)d_in[1];   // [1024, 512]
    const float* b1 = (const float*)d_in[2];   // [1024]
    const float* W2 = (const float*)d_in[3];   // [496, 1024]
    const float* b2 = (const float*)d_in[4];   // [496]
    float* out = (float*)d_out;                // [16384, 32, 32]

    float* h  = out;              // d_out (64 MB) doubles as h scratch
    float* cs = (float*)d_ws;     // [16384][496] float2 = 65 MB

    gemm_nt_mfma<0><<<dim3(HIDDEN / 128, BATCH / 128), 256, 0, stream>>>(
        x, W1, b1, h, BATCH, HIDDEN, INPUT_DIM, HIDDEN);

    gemm_nt_mfma<1><<<dim3((NANG + 127) / 128, BATCH / 128), 256, 0, stream>>>(
        h, W2, b2, cs, BATCH, NANG, HIDDEN, NANG);

    rotate_kernel<<<dim3(BATCH * NROT / 256), 256, 0, stream>>>(
        (const float4*)cs, out);
}

// Round 8
// 149.071 us; speedup vs baseline: 2.7616x; 2.7616x over previous
//
#include <hip/hip_runtime.h>
#include <math.h>
#include <utility>

#define BATCH 16384
#define INPUT_DIM 512
#define HIDDEN 1024
#define NROT 32
#define NANG 496   // 32*31/2

typedef _Float16 half8 __attribute__((ext_vector_type(8)));
typedef float    f32x4 __attribute__((ext_vector_type(4)));

// ---------------------------------------------------------------------------
// Split-precision f16 MFMA GEMM (NT): C = epi(A[M,K] @ B[N,K]^T + bias)
// (unchanged — known-good since round 2)
// ---------------------------------------------------------------------------
template<int EPI>
__global__ __launch_bounds__(256) void gemm_nt_mfma(
    const float* __restrict__ A, const float* __restrict__ B,
    const float* __restrict__ bias, float* __restrict__ C,
    int M, int N, int K, int Nout)
{
    constexpr int BK = 32;                    // K per stage (f32 elems)
    __shared__ _Float16 sAh[2][128 * BK];
    __shared__ _Float16 sAl[2][128 * BK];
    __shared__ _Float16 sB [2][128 * BK];     // total 48 KB

    const int tid = threadIdx.x;
    const int m0 = blockIdx.y * 128;
    const int n0 = blockIdx.x * 128;

    const int rA  = tid >> 2;                       // 0..63
    const int k8  = tid & 3;
    const int swW = ((k8 ^ (rA & 3)) << 3);         // swizzled f16 offset in row

    float4 rg[4][2];

    auto load_tile = [&](int kt) {
        const size_t koff = (size_t)kt * BK + k8 * 8;
        const float4* p;
        p = (const float4*)(A + (size_t)(m0 + rA) * K + koff);
        rg[0][0] = p[0]; rg[0][1] = p[1];
        p = (const float4*)(A + (size_t)(m0 + rA + 64) * K + koff);
        rg[1][0] = p[0]; rg[1][1] = p[1];
        const float4 z = make_float4(0.f, 0.f, 0.f, 0.f);
        if (EPI == 0 || (n0 + rA) < N) {
            p = (const float4*)(B + (size_t)(n0 + rA) * K + koff);
            rg[2][0] = p[0]; rg[2][1] = p[1];
        } else { rg[2][0] = z; rg[2][1] = z; }
        if (EPI == 0 || (n0 + rA + 64) < N) {
            p = (const float4*)(B + (size_t)(n0 + rA + 64) * K + koff);
            rg[3][0] = p[0]; rg[3][1] = p[1];
        } else { rg[3][0] = z; rg[3][1] = z; }
    };

    auto cvt_write = [&](int buf) {
        #pragma unroll
        for (int h = 0; h < 2; ++h) {
            const int base = (rA + h * 64) * BK + swW;
            half8 hi, lo;
            const float* f = (const float*)&rg[h][0];
            #pragma unroll
            for (int j = 0; j < 8; ++j) {
                _Float16 hv = (_Float16)f[j];
                hi[j] = hv;
                lo[j] = (_Float16)(f[j] - (float)hv);
            }
            *(half8*)&sAh[buf][base] = hi;
            *(half8*)&sAl[buf][base] = lo;
        }
        #pragma unroll
        for (int h = 0; h < 2; ++h) {
            const int base = (rA + h * 64) * BK + swW;
            half8 bv;
            const float* f = (const float*)&rg[2 + h][0];
            #pragma unroll
            for (int j = 0; j < 8; ++j) bv[j] = (_Float16)f[j];
            *(half8*)&sB[buf][base] = bv;
        }
    };

    const int lane = tid & 63;
    const int wid  = tid >> 6;
    const int wr = wid >> 1, wc = wid & 1;
    const int fr = lane & 15, fq = lane >> 4;
    const int swR   = ((fq ^ (fr & 3)) << 3);
    const int aBase = (wr * 64 + fr) * BK + swR;
    const int bBase = (wc * 64 + fr) * BK + swR;

    f32x4 acc[4][4];
    #pragma unroll
    for (int i = 0; i < 4; ++i)
        #pragma unroll
        for (int j = 0; j < 4; ++j) acc[i][j] = (f32x4)(0.f);

    const int NT = K / BK;
    load_tile(0);
    cvt_write(0);
    int cur = 0;

    for (int kt = 0; kt < NT; ++kt) {
        const bool more = (kt + 1 < NT);
        if (more) load_tile(kt + 1);
        __syncthreads();

        half8 ah[4], al[4], bb[4];
        #pragma unroll
        for (int f = 0; f < 4; ++f) {
            ah[f] = *(const half8*)&sAh[cur][aBase + f * 16 * BK];
            al[f] = *(const half8*)&sAl[cur][aBase + f * 16 * BK];
            bb[f] = *(const half8*)&sB [cur][bBase + f * 16 * BK];
        }
        #pragma unroll
        for (int fm = 0; fm < 4; ++fm)
            #pragma unroll
            for (int fn = 0; fn < 4; ++fn) {
                acc[fm][fn] = __builtin_amdgcn_mfma_f32_16x16x32_f16(
                    al[fm], bb[fn], acc[fm][fn], 0, 0, 0);
                acc[fm][fn] = __builtin_amdgcn_mfma_f32_16x16x32_f16(
                    ah[fm], bb[fn], acc[fm][fn], 0, 0, 0);
            }

        if (more) cvt_write(cur ^ 1);
        cur ^= 1;
    }

    if (EPI == 0) {
        #pragma unroll
        for (int fn = 0; fn < 4; ++fn) {
            const int col = n0 + wc * 64 + fn * 16 + fr;
            const float bv = bias[col];
            #pragma unroll
            for (int fm = 0; fm < 4; ++fm) {
                const int row0 = m0 + wr * 64 + fm * 16 + fq * 4;
                #pragma unroll
                for (int r = 0; r < 4; ++r)
                    C[(size_t)(row0 + r) * Nout + col] =
                        fmaxf(acc[fm][fn][r] + bv, 0.f);
            }
        }
    } else {
        #pragma unroll
        for (int fn = 0; fn < 4; ++fn) {
            const int col = n0 + wc * 64 + fn * 16 + fr;
            if (col < Nout) {
                const float bv = bias[col];
                #pragma unroll
                for (int fm = 0; fm < 4; ++fm) {
                    const int row0 = m0 + wr * 64 + fm * 16 + fq * 4;
                    #pragma unroll
                    for (int r = 0; r < 4; ++r) {
                        const float ang = acc[fm][fn][r] + bv;
                        float s, c;
                        __sincosf(ang, &s, &c);
                        *(float2*)(C + ((size_t)(row0 + r) * Nout + col) * 2) =
                            make_float2(c, s);
                    }
                }
            }
        }
    }
}

// ---------------------------------------------------------------------------
// Givens rotation chain — LDS-staged, 4-deep ds_read_b128 groups:
//   - Block = 128 threads = 4 batch elements x 32 rows.
//   - cs for the block's 4 batches staged once into 16KB LDS (coalesced).
//   - Chain processed in 62 groups of 8 rotations: 4 independent
//     ds_read_b128 (compile-time offsets) then 32 VALU ops. Group G+1's
//     reads are independent of group G's FMAs -> compiler overlaps them;
//     LDS latency (~60cyc) amortized 4-deep instead of exposed 496 times
//     (round-2/4 failure mode). No inline asm, no register ring -> the
//     allocator stays in safe territory (~56 VGPRs, like round 4).
//   - Output via XOR-swizzled LDS transpose (same 16KB buffer, after a
//     barrier) -> contiguous global stores (round-4's WRITE_SIZE fix).
// ---------------------------------------------------------------------------
struct IJTbl { unsigned char i[NANG]; unsigned char j[NANG]; };
constexpr IJTbl make_ij_tbl() {
    IJTbl t{};
    int k = 0;
    for (int i = 0; i < NROT - 1; ++i)
        for (int j = i + 1; j < NROT; ++j) { t.i[k] = (unsigned char)i; t.j[k] = (unsigned char)j; ++k; }
    return t;
}
constexpr IJTbl IJT = make_ij_tbl();

constexpr int NF4 = NANG / 2;     // 248 float4s per batch (2 rotations each)
constexpr int BPB = 4;            // batches per block (128 threads)

template<int M>   // M = f4 index 0..247: rotations 2M, 2M+1
__device__ __forceinline__ void rot_pair(const f32x4 q, float (&v)[NROT]) {
    {
        constexpr int k = 2 * M;
        constexpr int i = IJT.i[k], j = IJT.j[k];
        const float vi = v[i], vj = v[j];
        v[i] = fmaf(q[0], vi,  q[1] * vj);
        v[j] = fmaf(q[0], vj, -q[1] * vi);
    }
    {
        constexpr int k = 2 * M + 1;
        constexpr int i = IJT.i[k], j = IJT.j[k];
        const float vi = v[i], vj = v[j];
        v[i] = fmaf(q[2], vi,  q[3] * vj);
        v[j] = fmaf(q[2], vj, -q[3] * vi);
    }
}

template<int G>   // G = group 0..61: f4 indices 4G..4G+3 (8 rotations)
__device__ __forceinline__ void group_step(const float* __restrict__ lcs,
                                           float (&v)[NROT]) {
    const f32x4 s0 = *(const f32x4*)(lcs + (G * 4 + 0) * 4);
    const f32x4 s1 = *(const f32x4*)(lcs + (G * 4 + 1) * 4);
    const f32x4 s2 = *(const f32x4*)(lcs + (G * 4 + 2) * 4);
    const f32x4 s3 = *(const f32x4*)(lcs + (G * 4 + 3) * 4);
    rot_pair<G * 4 + 0>(s0, v);
    rot_pair<G * 4 + 1>(s1, v);
    rot_pair<G * 4 + 2>(s2, v);
    rot_pair<G * 4 + 3>(s3, v);
}

template<size_t... Gs>
__device__ __forceinline__ void run_groups(const float* __restrict__ lcs,
                                           float (&v)[NROT],
                                           std::index_sequence<Gs...>) {
    (group_step<(int)Gs>(lcs, v), ...);
}

__global__ __launch_bounds__(128) void rotate_kernel(
    const float4* __restrict__ cs4, float* __restrict__ out)
{
    __shared__ float lds[BPB * NF4 * 4];   // 15,872 B; also reused for transpose

    const int tid = threadIdx.x;
    const int bl  = tid >> 5;              // batch within block (0..3)
    const int r   = tid & 31;              // row of R

    // ---- stage 4 batches of cs (992 float4) coalesced ----
    const float4* gsrc = cs4 + (size_t)blockIdx.x * (BPB * NF4);
    float4* l4 = (float4*)lds;
    #pragma unroll
    for (int t = 0; t < 8; ++t) {
        const int idx = t * 128 + tid;
        if (idx < BPB * NF4) l4[idx] = gsrc[idx];
    }
    __syncthreads();

    float v[NROT];
    #pragma unroll
    for (int c = 0; c < NROT; ++c) v[c] = (c == r) ? 1.f : 0.f;

    const float* lcs = lds + bl * NF4 * 4;   // this batch's 248 f4
    run_groups(lcs, v, std::make_index_sequence<62>{});

    __syncthreads();   // all staged-cs reads done before overwrite

    // ---- coalesced store via swizzled LDS transpose ----
    #pragma unroll
    for (int q = 0; q < 8; ++q) {
        *(float4*)&lds[tid * 32 + ((q ^ (tid & 7)) << 2)] =
            make_float4(v[q*4], v[q*4+1], v[q*4+2], v[q*4+3]);
    }
    __syncthreads();

    float* obase = out + (size_t)blockIdx.x * (BPB * NROT * NROT);
    #pragma unroll
    for (int s = 0; s < 8; ++s) {
        const int f4  = s * 128 + tid;
        const int row = f4 >> 3;
        const int qq  = f4 & 7;
        const float4 val = *(const float4*)&lds[row * 32 + ((qq ^ (row & 7)) << 2)];
        *(float4*)(obase + (size_t)f4 * 4) = val;
    }
}

// ---------------------------------------------------------------------------
extern "C" void kernel_launch(void* const* d_in, const int* in_sizes, int n_in,
                              void* d_out, int out_size, void* d_ws, size_t ws_size,
                              hipStream_t stream)
{
    const float* x  = (const float*)d_in[0];   // [16384, 512]
    const float* W1 = (const float*)d_in[1];   // [1024, 512]
    const float* b1 = (const float*)d_in[2];   // [1024]
    const float* W2 = (const float*)d_in[3];   // [496, 1024]
    const float* b2 = (const float*)d_in[4];   // [496]
    float* out = (float*)d_out;                // [16384, 32, 32]

    float* h  = out;              // d_out (64 MB) doubles as h scratch
    float* cs = (float*)d_ws;     // [16384][496] float2 = 65 MB

    gemm_nt_mfma<0><<<dim3(HIDDEN / 128, BATCH / 128), 256, 0, stream>>>(
        x, W1, b1, h, BATCH, HIDDEN, INPUT_DIM, HIDDEN);

    gemm_nt_mfma<1><<<dim3((NANG + 127) / 128, BATCH / 128), 256, 0, stream>>>(
        h, W2, b2, cs, BATCH, NANG, HIDDEN, NANG);

    rotate_kernel<<<dim3(BATCH / BPB), 128, 0, stream>>>(
        (const float4*)cs, out);
}

// Round 9
// 138.586 us; speedup vs baseline: 2.9705x; 1.0757x over previous
//
#include <hip/hip_runtime.h>
#include <math.h>
#include <utility>

#define BATCH 16384
#define INPUT_DIM 512
#define HIDDEN 1024
#define NROT 32
#define NANG 496   // 32*31/2

typedef _Float16 half8 __attribute__((ext_vector_type(8)));
typedef float    f32x4 __attribute__((ext_vector_type(4)));
typedef float    f32x2 __attribute__((ext_vector_type(2)));

// ---------------------------------------------------------------------------
// Split-precision f16 MFMA GEMM (NT): C = epi(A[M,K] @ B[N,K]^T + bias)
// (unchanged — known-good since round 2)
// ---------------------------------------------------------------------------
template<int EPI>
__global__ __launch_bounds__(256) void gemm_nt_mfma(
    const float* __restrict__ A, const float* __restrict__ B,
    const float* __restrict__ bias, float* __restrict__ C,
    int M, int N, int K, int Nout)
{
    constexpr int BK = 32;                    // K per stage (f32 elems)
    __shared__ _Float16 sAh[2][128 * BK];
    __shared__ _Float16 sAl[2][128 * BK];
    __shared__ _Float16 sB [2][128 * BK];     // total 48 KB

    const int tid = threadIdx.x;
    const int m0 = blockIdx.y * 128;
    const int n0 = blockIdx.x * 128;

    const int rA  = tid >> 2;                       // 0..63
    const int k8  = tid & 3;
    const int swW = ((k8 ^ (rA & 3)) << 3);         // swizzled f16 offset in row

    float4 rg[4][2];

    auto load_tile = [&](int kt) {
        const size_t koff = (size_t)kt * BK + k8 * 8;
        const float4* p;
        p = (const float4*)(A + (size_t)(m0 + rA) * K + koff);
        rg[0][0] = p[0]; rg[0][1] = p[1];
        p = (const float4*)(A + (size_t)(m0 + rA + 64) * K + koff);
        rg[1][0] = p[0]; rg[1][1] = p[1];
        const float4 z = make_float4(0.f, 0.f, 0.f, 0.f);
        if (EPI == 0 || (n0 + rA) < N) {
            p = (const float4*)(B + (size_t)(n0 + rA) * K + koff);
            rg[2][0] = p[0]; rg[2][1] = p[1];
        } else { rg[2][0] = z; rg[2][1] = z; }
        if (EPI == 0 || (n0 + rA + 64) < N) {
            p = (const float4*)(B + (size_t)(n0 + rA + 64) * K + koff);
            rg[3][0] = p[0]; rg[3][1] = p[1];
        } else { rg[3][0] = z; rg[3][1] = z; }
    };

    auto cvt_write = [&](int buf) {
        #pragma unroll
        for (int h = 0; h < 2; ++h) {
            const int base = (rA + h * 64) * BK + swW;
            half8 hi, lo;
            const float* f = (const float*)&rg[h][0];
            #pragma unroll
            for (int j = 0; j < 8; ++j) {
                _Float16 hv = (_Float16)f[j];
                hi[j] = hv;
                lo[j] = (_Float16)(f[j] - (float)hv);
            }
            *(half8*)&sAh[buf][base] = hi;
            *(half8*)&sAl[buf][base] = lo;
        }
        #pragma unroll
        for (int h = 0; h < 2; ++h) {
            const int base = (rA + h * 64) * BK + swW;
            half8 bv;
            const float* f = (const float*)&rg[2 + h][0];
            #pragma unroll
            for (int j = 0; j < 8; ++j) bv[j] = (_Float16)f[j];
            *(half8*)&sB[buf][base] = bv;
        }
    };

    const int lane = tid & 63;
    const int wid  = tid >> 6;
    const int wr = wid >> 1, wc = wid & 1;
    const int fr = lane & 15, fq = lane >> 4;
    const int swR   = ((fq ^ (fr & 3)) << 3);
    const int aBase = (wr * 64 + fr) * BK + swR;
    const int bBase = (wc * 64 + fr) * BK + swR;

    f32x4 acc[4][4];
    #pragma unroll
    for (int i = 0; i < 4; ++i)
        #pragma unroll
        for (int j = 0; j < 4; ++j) acc[i][j] = (f32x4)(0.f);

    const int NT = K / BK;
    load_tile(0);
    cvt_write(0);
    int cur = 0;

    for (int kt = 0; kt < NT; ++kt) {
        const bool more = (kt + 1 < NT);
        if (more) load_tile(kt + 1);
        __syncthreads();

        half8 ah[4], al[4], bb[4];
        #pragma unroll
        for (int f = 0; f < 4; ++f) {
            ah[f] = *(const half8*)&sAh[cur][aBase + f * 16 * BK];
            al[f] = *(const half8*)&sAl[cur][aBase + f * 16 * BK];
            bb[f] = *(const half8*)&sB [cur][bBase + f * 16 * BK];
        }
        #pragma unroll
        for (int fm = 0; fm < 4; ++fm)
            #pragma unroll
            for (int fn = 0; fn < 4; ++fn) {
                acc[fm][fn] = __builtin_amdgcn_mfma_f32_16x16x32_f16(
                    al[fm], bb[fn], acc[fm][fn], 0, 0, 0);
                acc[fm][fn] = __builtin_amdgcn_mfma_f32_16x16x32_f16(
                    ah[fm], bb[fn], acc[fm][fn], 0, 0, 0);
            }

        if (more) cvt_write(cur ^ 1);
        cur ^= 1;
    }

    if (EPI == 0) {
        #pragma unroll
        for (int fn = 0; fn < 4; ++fn) {
            const int col = n0 + wc * 64 + fn * 16 + fr;
            const float bv = bias[col];
            #pragma unroll
            for (int fm = 0; fm < 4; ++fm) {
                const int row0 = m0 + wr * 64 + fm * 16 + fq * 4;
                #pragma unroll
                for (int r = 0; r < 4; ++r)
                    C[(size_t)(row0 + r) * Nout + col] =
                        fmaxf(acc[fm][fn][r] + bv, 0.f);
            }
        }
    } else {
        #pragma unroll
        for (int fn = 0; fn < 4; ++fn) {
            const int col = n0 + wc * 64 + fn * 16 + fr;
            if (col < Nout) {
                const float bv = bias[col];
                #pragma unroll
                for (int fm = 0; fm < 4; ++fm) {
                    const int row0 = m0 + wr * 64 + fm * 16 + fq * 4;
                    #pragma unroll
                    for (int r = 0; r < 4; ++r) {
                        const float ang = acc[fm][fn][r] + bv;
                        float s, c;
                        __sincosf(ang, &s, &c);
                        *(float2*)(C + ((size_t)(row0 + r) * Nout + col) * 2) =
                            make_float2(c, s);
                    }
                }
            }
        }
    }
}

// ---------------------------------------------------------------------------
// Givens rotation chain — packed-FP32, two rows per thread:
//   - Thread = (batch, row-pair): rows rp and rp+16 of ONE batch, held as 32
//     f32x2 pairs. Both rows share each rotation's (c,s), so one v_pk_*_f32
//     does both rows' work: 4 pk instrs / rotation = 2 instr/rotation/row
//     (VALU issue halves vs round 8), and per-CU ds_read count also halves
//     (16 waves x 248 reads instead of 32 x 248).
//   - (c,s) splat from the packed (c,s) register pair is free via VOP3P
//     op_sel/op_sel_hi modifiers — no movs. Inline asm is register-only and
//     synchronous (none of the round-6/7 allocator/async hazards).
//   - cs staged in 2 half-chains of 124 float4/batch, stride 125 (the 4
//     half-wave broadcast addresses land in 4 distinct banks). 16 KB LDS,
//     reused for the output transpose -> 10 blocks/CU.
// ---------------------------------------------------------------------------
struct IJTbl { unsigned char i[NANG]; unsigned char j[NANG]; };
constexpr IJTbl make_ij_tbl() {
    IJTbl t{};
    int k = 0;
    for (int i = 0; i < NROT - 1; ++i)
        for (int j = i + 1; j < NROT; ++j) { t.i[k] = (unsigned char)i; t.j[k] = (unsigned char)j; ++k; }
    return t;
}
constexpr IJTbl IJT = make_ij_tbl();

__device__ __forceinline__ f32x2 lo2(const f32x4 q) { return __builtin_shufflevector(q, q, 0, 1); }
__device__ __forceinline__ f32x2 hi2(const f32x4 q) { return __builtin_shufflevector(q, q, 2, 3); }

// One rotation K on the row-pair state. p = (c, s) packed in a VGPR pair.
template<int K>
__device__ __forceinline__ void rot_one(const f32x2 p, f32x2 (&v)[NROT]) {
    constexpr int i = IJT.i[K], j = IJT.j[K];
    f32x2 t0, t1, ni, nj;
    // t0 = s (.) vj   (src0 splats its HI half = s)
    asm("v_pk_mul_f32 %0, %1, %2 op_sel:[1,0] op_sel_hi:[1,1]"
        : "=v"(t0) : "v"(p), "v"(v[j]));
    // t1 = s (.) vi
    asm("v_pk_mul_f32 %0, %1, %2 op_sel:[1,0] op_sel_hi:[1,1]"
        : "=v"(t1) : "v"(p), "v"(v[i]));
    // ni = c (.) vi + t0   (src0 splats its LO half = c)
    asm("v_pk_fma_f32 %0, %1, %2, %3 op_sel:[0,0,0] op_sel_hi:[0,1,1]"
        : "=v"(ni) : "v"(p), "v"(v[i]), "v"(t0));
    // nj = c (.) vj - t1   (neg on src2)
    asm("v_pk_fma_f32 %0, %1, %2, %3 op_sel:[0,0,0] op_sel_hi:[0,1,1] neg_lo:[0,0,1] neg_hi:[0,0,1]"
        : "=v"(nj) : "v"(p), "v"(v[j]), "v"(t1));
    v[i] = ni; v[j] = nj;
}

// Group = 4 float4 (8 rotations) from this batch's staged half-chain.
template<int G, int H>
__device__ __forceinline__ void group_step(const float* __restrict__ lcs,
                                           f32x2 (&v)[NROT]) {
    const f32x4 q0 = *(const f32x4*)(lcs + (G * 4 + 0) * 4);
    const f32x4 q1 = *(const f32x4*)(lcs + (G * 4 + 1) * 4);
    const f32x4 q2 = *(const f32x4*)(lcs + (G * 4 + 2) * 4);
    const f32x4 q3 = *(const f32x4*)(lcs + (G * 4 + 3) * 4);
    constexpr int KB = (H * 124 + G * 4) * 2;   // absolute rotation base
    rot_one<KB + 0>(lo2(q0), v); rot_one<KB + 1>(hi2(q0), v);
    rot_one<KB + 2>(lo2(q1), v); rot_one<KB + 3>(hi2(q1), v);
    rot_one<KB + 4>(lo2(q2), v); rot_one<KB + 5>(hi2(q2), v);
    rot_one<KB + 6>(lo2(q3), v); rot_one<KB + 7>(hi2(q3), v);
}

template<int H, size_t... Gs>
__device__ __forceinline__ void run_half(const float* __restrict__ lcs,
                                         f32x2 (&v)[NROT],
                                         std::index_sequence<Gs...>) {
    (group_step<(int)Gs, H>(lcs, v), ...);
}

__global__ __launch_bounds__(128) void rotate_kernel(
    const float4* __restrict__ cs4, float* __restrict__ out)
{
    __shared__ float lds[4096];            // 16 KB (staging + output transpose)

    const int tid = threadIdx.x;
    const int bl  = tid >> 4;              // batch within block (0..7)
    const int rp  = tid & 15;              // row pair: rows rp, rp+16
    const size_t bbase = (size_t)blockIdx.x * 8;

    f32x2 v[NROT];
    #pragma unroll
    for (int c = 0; c < NROT; ++c) {
        f32x2 iv;
        iv[0] = (c == rp)      ? 1.f : 0.f;
        iv[1] = (c == rp + 16) ? 1.f : 0.f;
        v[c] = iv;
    }

    const float4* gsrc = cs4 + bbase * 248;          // 8 batches x 248 f4
    float4* l4 = (float4*)lds;                        // [8][125] (pad: banks)
    const float* lcs = lds + (bl * 125) * 4;

    #pragma unroll
    for (int h = 0; h < 2; ++h) {
        if (h) __syncthreads();            // previous half's reads complete
        #pragma unroll
        for (int it = 0; it < 8; ++it) {
            const int t = it * 128 + tid;
            if (t < 992) {
                const int b = t / 124, m = t - b * 124;
                l4[b * 125 + m] = gsrc[b * 248 + h * 124 + m];
            }
        }
        __syncthreads();
        if (h == 0) run_half<0>(lcs, v, std::make_index_sequence<31>{});
        else        run_half<1>(lcs, v, std::make_index_sequence<31>{});
    }
    __syncthreads();                       // chain reads done; reuse lds

    // ---- output: 2 phases (row rp, then row rp+16), swizzled transpose ----
    float* obase = out + bbase * (NROT * NROT);
    #pragma unroll
    for (int ph = 0; ph < 2; ++ph) {
        if (ph) __syncthreads();
        #pragma unroll
        for (int q = 0; q < 8; ++q) {
            float4 val = make_float4(v[q*4+0][ph], v[q*4+1][ph],
                                     v[q*4+2][ph], v[q*4+3][ph]);
            *(float4*)&lds[tid * 32 + ((q ^ (tid & 7)) << 2)] = val;
        }
        __syncthreads();
        #pragma unroll
        for (int s = 0; s < 8; ++s) {
            const int f4i = s * 128 + tid;           // 0..1023
            const int b   = f4i >> 7;                // batch 0..7
            const int rl  = (f4i >> 3) & 15;         // local row 0..15
            const int qq  = f4i & 7;
            const float4 val =
                *(const float4*)&lds[(b * 16 + rl) * 32 + ((qq ^ (rl & 7)) << 2)];
            *(float4*)(obase + (size_t)b * 1024 + (ph * 16 + rl) * 32 + qq * 4) = val;
        }
    }
}

// ---------------------------------------------------------------------------
extern "C" void kernel_launch(void* const* d_in, const int* in_sizes, int n_in,
                              void* d_out, int out_size, void* d_ws, size_t ws_size,
                              hipStream_t stream)
{
    const float* x  = (const float*)d_in[0];   // [16384, 512]
    const float* W1 = (const float*)d_in[1];   // [1024, 512]
    const float* b1 = (const float*)d_in[2];   // [1024]
    const float* W2 = (const float*)d_in[3];   // [496, 1024]
    const float* b2 = (const float*)d_in[4];   // [496]
    float* out = (float*)d_out;                // [16384, 32, 32]

    float* h  = out;              // d_out (64 MB) doubles as h scratch
    float* cs = (float*)d_ws;     // [16384][496] float2 = 65 MB

    gemm_nt_mfma<0><<<dim3(HIDDEN / 128, BATCH / 128), 256, 0, stream>>>(
        x, W1, b1, h, BATCH, HIDDEN, INPUT_DIM, HIDDEN);

    gemm_nt_mfma<1><<<dim3((NANG + 127) / 128, BATCH / 128), 256, 0, stream>>>(
        h, W2, b2, cs, BATCH, NANG, HIDDEN, NANG);

    rotate_kernel<<<dim3(BATCH / 8), 128, 0, stream>>>(
        (const float4*)cs, out);
}